// Round 4
// baseline (10391.211 us; speedup 1.0000x reference)
//
#include <hip/hip_runtime.h>
#include <cstdint>
#include <cstddef>

#define Bdim 256
#define Ndim 96
#define Edim 1024
#define HDdim 300
#define Ldim 2
#define LHdim 600
#define NCdim 7
#define GDdim 900              // HD*(L+1)
#define ROWS (Bdim*Ndim)       // 24576

typedef unsigned short u16;
typedef float f32x4 __attribute__((ext_vector_type(4)));
typedef short bf16x8 __attribute__((ext_vector_type(8)));

// Identity row-perm constants
#define IDP 0x7FFFFFFF, 1, 30, 0, 0

__device__ inline u16 f2bf(float x) {
    unsigned int u = __builtin_bit_cast(unsigned int, x);
    unsigned int r = (u + 0x7fffu + ((u >> 16) & 1u)) >> 16;   // RNE
    return (u16)r;
}
__device__ inline float bf2f(u16 h) {
    unsigned int u = ((unsigned int)h) << 16;
    return __builtin_bit_cast(float, u);
}

// ---------------------------------------------------------------------------
// fp32 GEMM (kept for fc1 / GAT V / MLP): C[m,n]=act(sum_k A[rowA(m),k]W[n,k]+b)
// ---------------------------------------------------------------------------
template<int ACT, int ACC>
__global__ __launch_bounds__(256) void gemm_tn(
    const float* __restrict__ A, int lda,
    int pmask, int pmul1, int pshift, int pmul2, int padd,
    const float* __restrict__ W, int ldw,
    float* __restrict__ C, int ldc,
    int M, int Nd, int K,
    const float* __restrict__ bias1,
    const float* __restrict__ bias2,
    const float* __restrict__ aptr)
{
    __shared__ __align__(16) float As[16][68];
    __shared__ __align__(16) float Ws[16][68];
    const int bm = blockIdx.x * 64;
    const int bn = blockIdx.y * 64;
    const int tid = threadIdx.x;
    const int lm  = tid & 63;
    const int lk4 = (tid >> 6) << 2;
    const int tm = (tid >> 4) << 2;
    const int tn = (tid & 15) << 2;
    float acc[4][4] = {{0.f,0.f,0.f,0.f},{0.f,0.f,0.f,0.f},{0.f,0.f,0.f,0.f},{0.f,0.f,0.f,0.f}};
    const int am = bm + lm;
    const int wn = bn + lm;
    const int rowA = (am & pmask) * pmul1 + (am >> pshift) * pmul2 + padd;

    for (int k0 = 0; k0 < K; k0 += 16) {
        float4 av, wv;
        const bool fullk = (k0 + 16 <= K);
        if (fullk) {
            av = (am < M)  ? *(const float4*)(A + (size_t)rowA * lda + k0 + lk4) : make_float4(0.f,0.f,0.f,0.f);
            wv = (wn < Nd) ? *(const float4*)(W + (size_t)wn   * ldw + k0 + lk4) : make_float4(0.f,0.f,0.f,0.f);
        } else {
            float ta[4], tw[4];
            #pragma unroll
            for (int u = 0; u < 4; ++u) {
                int k = k0 + lk4 + u;
                ta[u] = (am < M  && k < K) ? A[(size_t)rowA * lda + k] : 0.f;
                tw[u] = (wn < Nd && k < K) ? W[(size_t)wn   * ldw + k] : 0.f;
            }
            av = make_float4(ta[0],ta[1],ta[2],ta[3]);
            wv = make_float4(tw[0],tw[1],tw[2],tw[3]);
        }
        __syncthreads();
        As[lk4+0][lm] = av.x; As[lk4+1][lm] = av.y; As[lk4+2][lm] = av.z; As[lk4+3][lm] = av.w;
        Ws[lk4+0][lm] = wv.x; Ws[lk4+1][lm] = wv.y; Ws[lk4+2][lm] = wv.z; Ws[lk4+3][lm] = wv.w;
        __syncthreads();
        #pragma unroll
        for (int kk = 0; kk < 16; ++kk) {
            float a0[4], w0[4];
            *(float4*)a0 = *(const float4*)&As[kk][tm];
            *(float4*)w0 = *(const float4*)&Ws[kk][tn];
            #pragma unroll
            for (int i = 0; i < 4; ++i)
                #pragma unroll
                for (int j = 0; j < 4; ++j)
                    acc[i][j] = fmaf(a0[i], w0[j], acc[i][j]);
        }
    }

    const float aval = (ACT == 1) ? *aptr : 0.f;
    #pragma unroll
    for (int i = 0; i < 4; ++i) {
        int m = bm + tm + i;
        if (m >= M) continue;
        #pragma unroll
        for (int j = 0; j < 4; ++j) {
            int n = bn + tn + j;
            if (n >= Nd) continue;
            float v = acc[i][j];
            if (bias1) v += bias1[n];
            if (bias2) v += bias2[n];
            if (ACC)   v += C[(size_t)m * ldc + n];
            if (ACT == 1) v = (v >= 0.f) ? v : aval * v;
            C[(size_t)m * ldc + n] = v;
        }
    }
}

// ---------------------------------------------------------------------------
// bf16x3 split MFMA GEMM: C = act(sum_k (Ah+Al)[m,k]*(Wh+Wl)[n,k] + bias)
// A:(M,K) bf16 hi/lo; W:(N,K) bf16 hi/lo; K multiple of 32; lda/ldw mult of 8.
// OUT: 0 -> fp32 C; 1 -> split bf16 (Ch,Cl). ACT: 1 -> prelu(aptr).
// Tile 128x128, BK=32, 4 waves (2x2), wave tile 64x64 = 4x4 frags of 16x16x32.
// ---------------------------------------------------------------------------
template<int OUT, int ACT>
__global__ __launch_bounds__(256) void gemm_mfma3(
    const u16* __restrict__ Ah, const u16* __restrict__ Al, int lda,
    const u16* __restrict__ Wh, const u16* __restrict__ Wl, int ldw,
    float* __restrict__ C, u16* __restrict__ Ch, u16* __restrict__ Cl, int ldc,
    int M, int Nd, int K,
    const float* __restrict__ bias, const float* __restrict__ aptr)
{
    __shared__ u16 AtH[4][1024];
    __shared__ u16 AtL[4][1024];
    __shared__ u16 WtH[4][1024];
    __shared__ u16 WtL[4][1024];
    const int tid  = threadIdx.x;
    const int bm   = blockIdx.x * 128;
    const int bn   = blockIdx.y * 128;
    const int wv   = tid >> 6;
    const int lane = tid & 63;
    const int wr   = (wv >> 1) * 64;
    const int wc   = (wv & 1) * 64;
    const int l15  = lane & 15;
    const int kseg = lane >> 4;

    f32x4 acc[4][4];
    #pragma unroll
    for (int i = 0; i < 4; ++i)
        #pragma unroll
        for (int j = 0; j < 4; ++j) acc[i][j] = (f32x4){0.f,0.f,0.f,0.f};

    const int srow = tid & 127;
    const bool isA = (tid < 128);
    const int gr   = isA ? (bm + srow) : (bn + srow);
    const int glim = isA ? M : Nd;
    const u16* pHbase = (isA ? Ah : Wh) + (size_t)gr * (isA ? lda : ldw);
    const u16* pLbase = (isA ? Al : Wl) + (size_t)gr * (isA ? lda : ldw);
    u16* dH = isA ? &AtH[0][0] : &WtH[0][0];
    u16* dL = isA ? &AtL[0][0] : &WtL[0][0];

    for (int k0 = 0; k0 < K; k0 += 32) {
        __syncthreads();
        {
            const bool ok = (gr < glim);
            #pragma unroll
            for (int s = 0; s < 4; ++s) {
                bf16x8 vH = {0,0,0,0,0,0,0,0};
                bf16x8 vL = {0,0,0,0,0,0,0,0};
                if (ok) {
                    vH = *(const bf16x8*)(pHbase + k0 + s * 8);
                    vL = *(const bf16x8*)(pLbase + k0 + s * 8);
                }
                *(bf16x8*)(dH + s * 1024 + srow * 8) = vH;
                *(bf16x8*)(dL + s * 1024 + srow * 8) = vL;
            }
        }
        __syncthreads();
        bf16x8 aH[4], aL[4], bH[4], bL[4];
        #pragma unroll
        for (int f = 0; f < 4; ++f) {
            int ar = wr + f * 16 + l15;
            int br = wc + f * 16 + l15;
            aH[f] = *(const bf16x8*)&AtH[kseg][ar * 8];
            aL[f] = *(const bf16x8*)&AtL[kseg][ar * 8];
            bH[f] = *(const bf16x8*)&WtH[kseg][br * 8];
            bL[f] = *(const bf16x8*)&WtL[kseg][br * 8];
        }
        #pragma unroll
        for (int i = 0; i < 4; ++i)
            #pragma unroll
            for (int j = 0; j < 4; ++j)
                acc[i][j] = __builtin_amdgcn_mfma_f32_16x16x32_bf16(aH[i], bH[j], acc[i][j], 0, 0, 0);
        #pragma unroll
        for (int i = 0; i < 4; ++i)
            #pragma unroll
            for (int j = 0; j < 4; ++j)
                acc[i][j] = __builtin_amdgcn_mfma_f32_16x16x32_bf16(aH[i], bL[j], acc[i][j], 0, 0, 0);
        #pragma unroll
        for (int i = 0; i < 4; ++i)
            #pragma unroll
            for (int j = 0; j < 4; ++j)
                acc[i][j] = __builtin_amdgcn_mfma_f32_16x16x32_bf16(aL[i], bH[j], acc[i][j], 0, 0, 0);
    }

    const float av = (ACT == 1) ? *aptr : 0.f;
    const int r4 = (lane >> 4) * 4;
    #pragma unroll
    for (int j = 0; j < 4; ++j) {
        int col = bn + wc + j * 16 + l15;
        if (col >= Nd) continue;
        float bv = bias ? bias[col] : 0.f;
        #pragma unroll
        for (int i = 0; i < 4; ++i) {
            #pragma unroll
            for (int rr = 0; rr < 4; ++rr) {
                int row = bm + wr + i * 16 + r4 + rr;
                if (row >= M) continue;
                float v = acc[i][j][rr] + bv;
                if (ACT == 1) v = (v >= 0.f) ? v : av * v;
                if (OUT == 0) {
                    C[(size_t)row * ldc + col] = v;
                } else {
                    u16 h = f2bf(v);
                    Ch[(size_t)row * ldc + col] = h;
                    Cl[(size_t)row * ldc + col] = f2bf(v - bf2f(h));
                }
            }
        }
    }
}

// ---------------------------------------------------------------------------
// split fp32 -> bf16 hi/lo with row perm, col zero-pad. dst[r][c], c<wcols.
// ---------------------------------------------------------------------------
__global__ __launch_bounds__(256) void split_rows(
    const float* __restrict__ src, int srcld,
    int pmask, int pmul1, int pshift, int pmul2, int padd,
    u16* __restrict__ dstH, u16* __restrict__ dstL, int dstld,
    int wcols, int validK)
{
    int r = blockIdx.y;
    int c = blockIdx.x * 256 + threadIdx.x;
    if (c >= wcols) return;
    int sr = (r & pmask) * pmul1 + (r >> pshift) * pmul2 + padd;
    float v = (c < validK) ? src[(size_t)sr * srcld + c] : 0.f;
    u16 h = f2bf(v);
    dstH[(size_t)r * dstld + c] = h;
    dstL[(size_t)r * dstld + c] = f2bf(v - bf2f(h));
}

// Whh rows permuted to gate-interleaved order: row' = u*4+g
__global__ __launch_bounds__(256) void whh_perm(const float* __restrict__ src, float* __restrict__ dst)
{
    int r = blockIdx.y;
    int c = blockIdx.x * 256 + threadIdx.x;
    if (c >= LHdim) return;
    int sr = (r & 3) * LHdim + (r >> 2);
    dst[(size_t)r * LHdim + c] = src[(size_t)sr * LHdim + c];
}

// biasP[n'] = b_ih[orig]+b_hh[orig], orig = (n'&3)*600+(n'>>2)
__global__ __launch_bounds__(256) void bias_perm(
    const float* __restrict__ bih, const float* __restrict__ bhh, float* __restrict__ dst)
{
    int n = blockIdx.x * 256 + threadIdx.x;
    if (n >= 4 * LHdim) return;
    int o = (n & 3) * LHdim + (n >> 2);
    dst[n] = bih[o] + bhh[o];
}

// ---------------------------------------------------------------------------
__global__ __launch_bounds__(256) void norm_kernel(const float* __restrict__ f, float* __restrict__ invn)
{
    int row  = blockIdx.x * 4 + (threadIdx.x >> 6);
    int lane = threadIdx.x & 63;
    const float* fr = f + (size_t)row * Edim;
    float ss = 0.f;
    for (int t = lane; t < Edim; t += 64) { float v = fr[t]; ss = fmaf(v, v, ss); }
    #pragma unroll
    for (int o = 32; o > 0; o >>= 1) ss += __shfl_down(ss, o);
    if (lane == 0) invn[row] = 1.f / (sqrtf(ss) + 1e-8f);
}

__global__ __launch_bounds__(256) void simadj_kernel(
    const float* __restrict__ f, const float* __restrict__ invn,
    const float* __restrict__ entro, const float* __restrict__ alphap,
    const float* __restrict__ thrp, uint8_t* __restrict__ adj)
{
    int b = blockIdx.x;
    __shared__ float S[16][100];
    int tid = threadIdx.x;
    int i0 = (tid >> 4) * 6, j0 = (tid & 15) * 6;
    float acc[6][6];
    #pragma unroll
    for (int i = 0; i < 6; ++i)
        #pragma unroll
        for (int j = 0; j < 6; ++j) acc[i][j] = 0.f;
    const float* fb = f + (size_t)b * Ndim * Edim;

    for (int k0 = 0; k0 < Edim; k0 += 16) {
        __syncthreads();
        #pragma unroll
        for (int r = 0; r < 6; ++r) {
            int n = (tid >> 4) + r * 16;
            S[tid & 15][n] = fb[(size_t)n * Edim + k0 + (tid & 15)];
        }
        __syncthreads();
        #pragma unroll
        for (int kk = 0; kk < 16; ++kk) {
            float a[6], bb[6];
            #pragma unroll
            for (int u = 0; u < 6; ++u) a[u] = S[kk][i0 + u];
            #pragma unroll
            for (int u = 0; u < 6; ++u) bb[u] = S[kk][j0 + u];
            #pragma unroll
            for (int i = 0; i < 6; ++i)
                #pragma unroll
                for (int j = 0; j < 6; ++j)
                    acc[i][j] = fmaf(a[i], bb[j], acc[i][j]);
        }
    }

    float alpha = *alphap, thr = *thrp;
    float onem = 1.f - alpha;
    #pragma unroll
    for (int i = 0; i < 6; ++i) {
        int ii = i0 + i;
        float inv_i = invn[b * Ndim + ii];
        #pragma unroll
        for (int j = 0; j < 6; ++j) {
            int jj = j0 + j;
            float simv = acc[i][j] * inv_i * invn[b * Ndim + jj];
            float comb = alpha * entro[b * Ndim + jj] + onem * simv;
            adj[((size_t)b * Ndim + ii) * Ndim + jj] = (comb > thr) ? 1 : 0;
        }
    }
}

__global__ __launch_bounds__(256) void qk_kernel(
    const float* __restrict__ Hsrc, const float* __restrict__ wqk,
    float* __restrict__ q, float* __restrict__ k)
{
    int row  = blockIdx.x * 4 + (threadIdx.x >> 6);
    int lane = threadIdx.x & 63;
    const float* h = Hsrc + (size_t)row * GDdim;
    float sq = 0.f, sk = 0.f;
    for (int t = lane; t < HDdim; t += 64) {
        float hv = h[t];
        sq = fmaf(hv, wqk[t], sq);
        sk = fmaf(hv, wqk[HDdim + t], sk);
    }
    #pragma unroll
    for (int o = 32; o > 0; o >>= 1) { sq += __shfl_down(sq, o); sk += __shfl_down(sk, o); }
    if (lane == 0) { q[row] = sq; k[row] = sk; }
}

__global__ __launch_bounds__(128) void gat_attn_kernel(
    const float* __restrict__ q, const float* __restrict__ k,
    const uint8_t* __restrict__ adj, const int* __restrict__ smask,
    const float* __restrict__ V0, const float* __restrict__ V1,
    const float* __restrict__ gbp,
    float* __restrict__ Mout)
{
    int r  = blockIdx.x;                 // storage row: i*256+b
    int i  = r >> 8;
    int b  = r & 255;
    int tid = threadIdx.x;
    __shared__ float w[128];
    __shared__ float red[128];
    float gb = *gbp;
    float sc = -1.0e9f;
    if (tid < Ndim) {
        uint8_t a = adj[((size_t)b * Ndim + i) * Ndim + tid];
        sc = a ? (q[r] + k[tid * Bdim + b] + gb) : -1.0e9f;
    }
    red[tid] = sc;
    __syncthreads();
    #pragma unroll
    for (int s = 64; s > 0; s >>= 1) { if (tid < s) red[tid] = fmaxf(red[tid], red[tid + s]); __syncthreads(); }
    float m = red[0];
    __syncthreads();
    float e = (tid < Ndim) ? expf(sc - m) : 0.f;
    w[tid] = e;
    red[tid] = e;
    __syncthreads();
    #pragma unroll
    for (int s = 64; s > 0; s >>= 1) { if (tid < s) red[tid] += red[tid + s]; __syncthreads(); }
    float inv = 1.f / red[0];
    __syncthreads();

    float a0 = 0.f, a1 = 0.f, a2 = 0.f;
    const int* sm = smask + ((size_t)b * Ndim + i) * Ndim;
    for (int j = 0; j < Ndim; ++j) {
        float wj = w[j];
        if (wj == 0.f) continue;
        const float* V = (sm[j] ? V0 : V1) + (size_t)(j * Bdim + b) * HDdim;
        a0 = fmaf(wj, V[tid], a0);
        a1 = fmaf(wj, V[tid + 128], a1);
        if (tid < HDdim - 256) a2 = fmaf(wj, V[tid + 256], a2);
    }
    float* mo = Mout + (size_t)r * GDdim;
    mo[tid]       = a0 * inv;
    mo[tid + 128] = a1 * inv;
    if (tid < HDdim - 256) mo[tid + 256] = a2 * inv;
}

__global__ __launch_bounds__(256) void zero_hc_kernel(float* __restrict__ h, float* __restrict__ c, int n)
{
    int i = blockIdx.x * 256 + threadIdx.x;
    if (i < n) { h[i] = 0.f; c[i] = 0.f; }
}

// ---------------------------------------------------------------------------
// Fused LSTM step: gates(b, n'=u*4+g) = h_in @ WhhP^T + zt; apply cell; write
// h_out/c_out (b,600) and Hl (row b, col u). Tile 32b x 64n', block 128.
// K=600 is NOT a multiple of 16: zero-pad the K-tail in LDS (chunks are
// 4-aligned and 600%4==0, so whole-chunk guards suffice).
// ---------------------------------------------------------------------------
__global__ __launch_bounds__(128) void lstm_step(
    const float* __restrict__ hin, const float* __restrict__ cin,
    const float* __restrict__ WhhP, const float* __restrict__ zt,
    float* __restrict__ hout, float* __restrict__ cout,
    float* __restrict__ Hl)
{
    __shared__ __align__(16) float Ht[16][36];
    __shared__ __align__(16) float Wt[16][68];
    const int tx = threadIdx.x;
    const int bm = blockIdx.x * 32;
    const int bn = blockIdx.y * 64;
    const int tm = (tx >> 4) << 2;       // 0..28
    const int tn = (tx & 15) << 2;       // 0..60
    float acc[4][4] = {{0.f,0.f,0.f,0.f},{0.f,0.f,0.f,0.f},{0.f,0.f,0.f,0.f},{0.f,0.f,0.f,0.f}};
    const int hb = tx & 31, hk = (tx >> 5) << 2;
    const int wn = tx & 63, wk = (tx >> 6) << 3;
    const int gn = bn + wn;
    const float4 fz = make_float4(0.f, 0.f, 0.f, 0.f);

    for (int k0 = 0; k0 < LHdim; k0 += 16) {
        __syncthreads();
        {
            float4 hv = (k0 + hk < LHdim)
                      ? *(const float4*)(hin + (size_t)(bm + hb) * LHdim + k0 + hk) : fz;
            Ht[hk+0][hb] = hv.x; Ht[hk+1][hb] = hv.y; Ht[hk+2][hb] = hv.z; Ht[hk+3][hb] = hv.w;
            if (gn < 4 * LHdim) {
                const float* wp = WhhP + (size_t)gn * LHdim + k0 + wk;
                float4 w0 = (k0 + wk     < LHdim) ? *(const float4*)wp       : fz;
                float4 w1 = (k0 + wk + 4 < LHdim) ? *(const float4*)(wp + 4) : fz;
                Wt[wk+0][wn] = w0.x; Wt[wk+1][wn] = w0.y; Wt[wk+2][wn] = w0.z; Wt[wk+3][wn] = w0.w;
                Wt[wk+4][wn] = w1.x; Wt[wk+5][wn] = w1.y; Wt[wk+6][wn] = w1.z; Wt[wk+7][wn] = w1.w;
            } else {
                #pragma unroll
                for (int u = 0; u < 8; ++u) Wt[wk+u][wn] = 0.f;
            }
        }
        __syncthreads();
        #pragma unroll
        for (int kk = 0; kk < 16; ++kk) {
            float a0[4], w0[4];
            *(float4*)a0 = *(const float4*)&Ht[kk][tm];
            *(float4*)w0 = *(const float4*)&Wt[kk][tn];
            #pragma unroll
            for (int i = 0; i < 4; ++i)
                #pragma unroll
                for (int j = 0; j < 4; ++j)
                    acc[i][j] = fmaf(a0[i], w0[j], acc[i][j]);
        }
    }

    int n0 = bn + tn;
    if (n0 < 4 * LHdim) {
        int u = n0 >> 2;
        #pragma unroll
        for (int i = 0; i < 4; ++i) {
            int b = bm + tm + i;
            const float* z = zt + (size_t)b * (4 * LHdim) + n0;
            float gi = acc[i][0] + z[0];
            float gf = acc[i][1] + z[1];
            float gg = acc[i][2] + z[2];
            float go = acc[i][3] + z[3];
            float si = 1.f / (1.f + expf(-gi));
            float sf = 1.f / (1.f + expf(-gf));
            float so = 1.f / (1.f + expf(-go));
            float cn = sf * cin[b * LHdim + u] + si * tanhf(gg);
            float hn = so * tanhf(cn);
            cout[b * LHdim + u] = cn;
            hout[b * LHdim + u] = hn;
            Hl[b * LHdim + u]   = hn;
        }
    }
}

__global__ __launch_bounds__(256) void out_kernel(
    const float* __restrict__ x, const float* __restrict__ ow,
    const float* __restrict__ ob, float* __restrict__ out)
{
    int r    = blockIdx.x * 4 + (threadIdx.x >> 6);
    int lane = threadIdx.x & 63;
    const float* xr = x + (size_t)r * HDdim;
    float acc[NCdim];
    #pragma unroll
    for (int n = 0; n < NCdim; ++n) acc[n] = 0.f;
    for (int t = lane; t < HDdim; t += 64) {
        float xv = xr[t];
        #pragma unroll
        for (int n = 0; n < NCdim; ++n) acc[n] = fmaf(xv, ow[n * HDdim + t], acc[n]);
    }
    #pragma unroll
    for (int o = 32; o > 0; o >>= 1)
        #pragma unroll
        for (int n = 0; n < NCdim; ++n) acc[n] += __shfl_down(acc[n], o);
    if (lane == 0) {
        int b = r & 255, nn = r >> 8;
        #pragma unroll
        for (int n = 0; n < NCdim; ++n) out[((size_t)b * Ndim + nn) * NCdim + n] = acc[n] + ob[n];
    }
}

// ---------------------------------------------------------------------------
extern "C" void kernel_launch(void* const* d_in, const int* in_sizes, int n_in,
                              void* d_out, int out_size, void* d_ws, size_t ws_size,
                              hipStream_t stream)
{
    const float*  features  = (const float*)d_in[0];
    const int*    s_mask    = (const int*)  d_in[1];
    const float*  entro     = (const float*)d_in[2];
    const float*  alpha     = (const float*)d_in[3];
    const float*  threshold = (const float*)d_in[4];
    const float*  fc1_w     = (const float*)d_in[5];
    const float*  fc1_b     = (const float*)d_in[6];
    const float*  gat_w     = (const float*)d_in[7];
    const float*  gat_b     = (const float*)d_in[8];
    const float*  wr0       = (const float*)d_in[9];
    const float*  wr1       = (const float*)d_in[10];
    const float*  enhance_w = (const float*)d_in[11];
    const float*  enhance_b = (const float*)d_in[12];
    const float*  prelu_a   = (const float*)d_in[13];
    const float*  lstm_w_ih = (const float*)d_in[14];
    const float*  lstm_w_hh = (const float*)d_in[15];
    const float*  lstm_b_ih = (const float*)d_in[16];
    const float*  lstm_b_hh = (const float*)d_in[17];
    const float*  mlp_w0    = (const float*)d_in[18];
    const float*  mlp_b0    = (const float*)d_in[19];
    const float*  mlp_a0    = (const float*)d_in[20];
    const float*  mlp_w1    = (const float*)d_in[21];
    const float*  mlp_b1    = (const float*)d_in[22];
    const float*  mlp_a1    = (const float*)d_in[23];
    const float*  out_w     = (const float*)d_in[24];
    const float*  out_b     = (const float*)d_in[25];
    float* out = (float*)d_out;
    char* ws = (char*)d_ws;

    // ---- fixed workspace layout (bytes, 256-aligned) ----
    uint8_t* adj   = (uint8_t*)(ws + 0);               //  2,359,296
    float*   invn  = (float*)(ws + 2359296);
    float*   qbuf  = (float*)(ws + 2457600);
    float*   kbuf  = (float*)(ws + 2555904);
    float*   biasP = (float*)(ws + 2654208);           //  9,600 (+pad)
    float*   h0    = (float*)(ws + 2663936);
    float*   c0    = (float*)(ws + 3278336);
    float*   h1    = (float*)(ws + 3892736);
    float*   c1    = (float*)(ws + 4507136);
    float*   WhhP  = (float*)(ws + 5121536);           //  5,760,000
    u16*     WihPH = (u16*)(ws + 10881536);            //  9,369,600 (2400 x 1952)
    u16*     WihPL = (u16*)(ws + 20251136);
    u16*     EwH   = (u16*)(ws + 29620736);            //  2,097,152 (1024 x 1024)
    u16*     EwL   = (u16*)(ws + 31717888);
    float*   Hcat  = (float*)(ws + 33815040);          // 88,473,600 (ROWS,900) n-major
    float*   V0    = (float*)(ws + 122288640);         // 29,491,200 (GAT)    } alias
    float*   V1    = (float*)(ws + 151779840);         // 29,491,200 (GAT)    } Hlstm
    float*   Hlstm = V0;                               // 58,982,400 (ROWS,600)
    float*   x1    = Hcat;                             // MLP scratch (Hcat dead)
    float*   x2    = (float*)(ws + 63306240);          // Hcat + 29,491,200

    // ---- tier selection for chunked seq/zin region ----
    const size_t fixedNeed = 181271040ull;
    const size_t perT = 5505024ull;                    // bytes per time-step
    int T;
    if      (ws_size >= fixedNeed + 96ull * perT) T = 96;   // 709.7 MB
    else if (ws_size >= fixedNeed + 32ull * perT) T = 32;   // 357.4 MB
    else if (ws_size >= fixedNeed + 16ull * perT) T = 16;   // 269.4 MB
    else if (ws_size >= fixedNeed +  8ull * perT) T = 8;    // 225.3 MB
    else if (ws_size >= fixedNeed +  4ull * perT) T = 4;    // 203.3 MB
    else return;                                            // visible failure
    char* cr = ws + fixedNeed;
    u16*   FHc  = (u16*)cr;                                         // (Mc,1024)
    u16*   FLc  = (u16*)(cr + (size_t)T *  524288);
    u16*   seqH = (u16*)(cr + (size_t)T * 1048576);                 // (Mc,1952)
    u16*   seqL = (u16*)(cr + (size_t)T * 1048576 + (size_t)T * 999424);
    float* zin  = (float*)(cr + (size_t)T * 1048576 + (size_t)T * 1998848);  // (Mc,2400)

    // 1) norms + adjacency
    norm_kernel<<<ROWS / 4, 256, 0, stream>>>(features, invn);
    simadj_kernel<<<Bdim, 256, 0, stream>>>(features, invn, entro, alpha, threshold, adj);

    // 2) H0 = prelu(features @ fc1_w^T + fc1_b) -> Hcat[:, 0:300] (n-major)
    gemm_tn<1,0><<<dim3(ROWS/64, 5), 256, 0, stream>>>(
        features, Edim, 255, Ndim, 8, 1, 0,
        fc1_w, Edim, Hcat, GDdim, ROWS, HDdim, Edim, fc1_b, nullptr, prelu_a);

    // 3) GAT layers
    for (int l = 0; l < Ldim; ++l) {
        const float* Hsrc = Hcat + l * HDdim;
        qk_kernel<<<ROWS / 4, 256, 0, stream>>>(Hsrc, gat_w + l * 2 * HDdim, qbuf, kbuf);
        gemm_tn<0,0><<<dim3(ROWS/64, 5), 256, 0, stream>>>(
            Hsrc, GDdim, IDP, wr0 + (size_t)l * HDdim * HDdim, HDdim,
            V0, HDdim, ROWS, HDdim, HDdim, nullptr, nullptr, nullptr);
        gemm_tn<0,0><<<dim3(ROWS/64, 5), 256, 0, stream>>>(
            Hsrc, GDdim, IDP, wr1 + (size_t)l * HDdim * HDdim, HDdim,
            V1, HDdim, ROWS, HDdim, HDdim, nullptr, nullptr, nullptr);
        gat_attn_kernel<<<ROWS, 128, 0, stream>>>(
            qbuf, kbuf, adj, s_mask, V0, V1, gat_b + l, Hcat + (l + 1) * HDdim);
    }

    // 4) weight conversions (bf16 hi/lo, gate-interleaved perms), state init
    split_rows<<<dim3(8, 4 * LHdim), 256, 0, stream>>>(
        lstm_w_ih, Edim + GDdim, 3, LHdim, 2, 1, 0, WihPH, WihPL, 1952, 1952, 1924);
    split_rows<<<dim3(4, Edim), 256, 0, stream>>>(
        enhance_w, Edim, IDP, EwH, EwL, Edim, Edim, Edim);
    whh_perm<<<dim3(3, 4 * LHdim), 256, 0, stream>>>(lstm_w_hh, WhhP);
    bias_perm<<<10, 256, 0, stream>>>(lstm_b_ih, lstm_b_hh, biasP);
    zero_hc_kernel<<<600, 256, 0, stream>>>(h0, c0, Bdim * LHdim);

    // 5) chunked: feat split -> enhance MFMA -> Hcat split -> zin MFMA -> LSTM steps
    float* hb[2] = {h0, h1};
    float* cb[2] = {c0, c1};
    int cur = 0;
    for (int t0 = 0; t0 < Ndim; t0 += T) {
        int Mc = T * Bdim;
        // features (b-major) -> chunk n-major bf16 hi/lo
        split_rows<<<dim3(4, Mc), 256, 0, stream>>>(
            features, Edim, 255, Ndim, 8, 1, t0, FHc, FLc, Edim, Edim, Edim);
        // seq[:, 0:1024] = prelu(F @ Ew^T + b) as split bf16
        gemm_mfma3<1,1><<<dim3(Mc/128, 8), 256, 0, stream>>>(
            FHc, FLc, Edim, EwH, EwL, Edim,
            nullptr, seqH, seqL, 1952, Mc, Edim, Edim, enhance_b, prelu_a);
        // seq[:, 1024:1952] = Hcat chunk (zero-padded 900..928)
        split_rows<<<dim3(4, Mc), 256, 0, stream>>>(
            Hcat, GDdim, 0x7FFFFFFF, 1, 30, 0, t0 * Bdim,
            seqH + 1024, seqL + 1024, 1952, 928, GDdim);
        // zin = seq @ WihP^T + biasP   (gate-interleaved columns)
        gemm_mfma3<0,0><<<dim3(Mc/128, 19), 256, 0, stream>>>(
            seqH, seqL, 1952, WihPH, WihPL, 1952,
            zin, nullptr, nullptr, 4 * LHdim, Mc, 4 * LHdim, 1952, biasP, nullptr);
        // LSTM steps
        for (int tl = 0; tl < T; ++tl) {
            lstm_step<<<dim3(8, 38), 128, 0, stream>>>(
                hb[cur], cb[cur], WhhP, zin + (size_t)tl * Bdim * 4 * LHdim,
                hb[cur ^ 1], cb[cur ^ 1],
                Hlstm + (size_t)(t0 + tl) * Bdim * LHdim);
            cur ^= 1;
        }
    }

    // 6) MLP head + output
    gemm_tn<1,0><<<dim3(ROWS/64, 5), 256, 0, stream>>>(
        Hlstm, LHdim, IDP, mlp_w0, LHdim, x1, HDdim, ROWS, HDdim, LHdim, mlp_b0, nullptr, mlp_a0);
    gemm_tn<1,0><<<dim3(ROWS/64, 5), 256, 0, stream>>>(
        x1, HDdim, IDP, mlp_w1, HDdim, x2, HDdim, ROWS, HDdim, HDdim, mlp_b1, nullptr, mlp_a1);
    out_kernel<<<ROWS / 4, 256, 0, stream>>>(x2, out_w, out_b, out);
}